// Round 9
// baseline (158.320 us; speedup 1.0000x reference)
//
#include <hip/hip_runtime.h>

// RecursiveNN: 11-level binary tree, shared linear map W(128x256)+b, bf16 MFMA.
// Evidence ledger (r0-r8): dur(tree128) fits a + bytes/BW with a ~= 36us
// (phase floor: ~35 phase-generations x ~1us, invariant across r4/r5/r6) and
// near-peak marginal BW; in-flight depth doesn't matter (r8 null: 25MB already
// in flight chip-wide). => attack the PHASE FLOOR algebraically.
// The level map is LINEAR: two levels collapse exactly into one quad level
//   out = W2.[a;b;c;d] + b2,  W2 = [WlWl|WlWr|WrWl|WrWr] (128x512),
//   b2 = (Wl+Wr)b + b.
// tree128: 256 leaves -> 64 -> 16 -> 4 roots in 6 compute phases (was 13);
// FLOPs -33%; per-phase cost identical to old step32 (32 MFMA, 16 ds_read).
// tree32: 32 ->(quad) 8 ->(quad) 2 ->(W1) 1: 4 phases (was 6).
// W2-frags: 16 resident regs (nl=0) + 16 streamed/phase from L2-hot wpack2
// (128KB, same addr across blocks -> broadcast). bf16 etab gather + raw
// barriers kept from r8. Numerics: 6 bf16 roundings along depth (was 11);
// W2 bf16-rounded from fp32 product -> error expected <= current.
// LDS: A/B/D 64-row STRIDE=136 bufs = 52224 B -> 3 blocks/CU; E overlays A.
// launch_bounds(256,3). Spill tripwire: WRITE_SIZE >> 2 MB, VGPR ~<=168.

typedef __bf16 bf16x8 __attribute__((ext_vector_type(8)));
typedef __bf16 bf16x4 __attribute__((ext_vector_type(4)));
typedef float f32x4 __attribute__((ext_vector_type(4)));

#define STRIDE 136  // 128 cols + 8 pad bf16 = 272B rows; 0 LDS conflicts measured

// Raw barrier: orders LDS ops across threads WITHOUT draining vmcnt.
#define BARRIER() do {                                          \
    asm volatile("s_waitcnt lgkmcnt(0)" ::: "memory");          \
    __builtin_amdgcn_s_barrier();                               \
} while (0)

// prep: blocks 0-15 pack W1 -> wpack1 (frag f: o=(2wv+nl)*16+(l&15),
// d=kk*32+(l>>4)*8, elem j = W[o][d+j]); blocks 16-47 compute+pack W2
// (f2=nl*16+kk, d in [0,512), quadrant s=d>>7: W2[o][d+j] =
// sum_k W[o, (s>>1)*128+k] * W[k, (s&1)*128 + (d&127)+j]); block 48: b2.
// All blocks grid-stride convert emb fp32 -> bf16 etab.
__global__ void prep_kernel(const float* __restrict__ W,
                            const float* __restrict__ bias,
                            const float* __restrict__ emb,
                            __bf16* __restrict__ wpack1,
                            __bf16* __restrict__ wpack2,
                            float* __restrict__ b2,
                            __bf16* __restrict__ etab, int n8) {
    const int tid = threadIdx.x;
    const int bx = blockIdx.x;
    const int wv = tid >> 6, l = tid & 63;
    if (bx < 16) {
        const int nl = bx >> 3, kk = bx & 7;
        const int o = ((wv << 1) + nl) * 16 + (l & 15);
        const int d = kk * 32 + ((l >> 4) << 3);
        const float* src = W + o * 256 + d;
        bf16x8 h;
#pragma unroll
        for (int j = 0; j < 8; ++j) h[j] = (__bf16)src[j];
        *(bf16x8*)(wpack1 + (size_t)(bx * 256 + tid) * 8) = h;
    } else if (bx < 48) {
        const int f2 = bx - 16;                  // 0..31
        const int nl = f2 >> 4, kk = f2 & 15;
        const int o = ((wv << 1) + nl) * 16 + (l & 15);
        const int d = kk * 32 + ((l >> 4) << 3); // 0..511, 8-elem block
        const int s = d >> 7, c = d & 127;       // quadrant, inner col
        const float* wrow = W + o * 256 + (s >> 1) * 128;
        const float* wcol = W + (s & 1) * 128 + c;
        float a8[8] = {0, 0, 0, 0, 0, 0, 0, 0};
        for (int k = 0; k < 128; ++k) {
            const float wl = wrow[k];
            const float* wr = wcol + k * 256;
#pragma unroll
            for (int j = 0; j < 8; ++j) a8[j] += wl * wr[j];
        }
        bf16x8 h;
#pragma unroll
        for (int j = 0; j < 8; ++j) h[j] = (__bf16)a8[j];
        *(bf16x8*)(wpack2 + (size_t)(f2 * 256 + tid) * 8) = h;
    } else if (bx == 48) {
        if (tid < 128) {
            float acc = bias[tid];
            const float* wr = W + tid * 256;
            for (int k = 0; k < 128; ++k)
                acc += (wr[k] + wr[128 + k]) * bias[k];
            b2[tid] = acc;
        }
    }
    const int stride = gridDim.x * blockDim.x;
    for (int i = bx * blockDim.x + tid; i < n8; i += stride) {
        const float* s = emb + (size_t)i * 8;
        const f32x4 a = *(const f32x4*)s;
        const f32x4 b = *(const f32x4*)(s + 4);
        const bf16x4 ha = __builtin_convertvector(a, bf16x4);
        const bf16x4 hb = __builtin_convertvector(b, bf16x4);
        bf16x8 h;
#pragma unroll
        for (int j = 0; j < 4; ++j) { h[j] = ha[j]; h[4 + j] = hb[j]; }
        *(bf16x8*)(etab + (size_t)i * 8) = h;
    }
}

// Quad-level accumulate: NOUT outputs (<=16) from 4*NOUT input rows stored at
// PERM rows s*NOUT+me (s = leaf-in-quad 0..3, me = output index). K=512 over
// 16 kk-frags; A K-index = kk*32 + q*8 + j == s*128 + lds_col (verified map).
// nl=0 frags from resident regs; nl=1 streamed from L2-hot wpack2.
template <int NOUT>
__device__ __forceinline__ void quad_acc_stream(
    const __bf16* src, const bf16x8* wres, const bf16x8* wp2,
    const float* b2v, int tid, int q, int lm, f32x4 (&acc)[2])
{
    const int me = (NOUT >= 16) ? lm : (lm < NOUT ? lm : 0);
    acc[0] = f32x4{ b2v[0], b2v[0], b2v[0], b2v[0] };
    acc[1] = f32x4{ b2v[1], b2v[1], b2v[1], b2v[1] };
#pragma unroll
    for (int kk = 0; kk < 16; ++kk) {
        const bf16x8 af = *(const bf16x8*)
            &src[((kk >> 2) * NOUT + me) * STRIDE + (kk & 3) * 32 + q * 8];
        acc[0] = __builtin_amdgcn_mfma_f32_16x16x32_bf16(
            af, wres[kk], acc[0], 0, 0, 0);
        acc[1] = __builtin_amdgcn_mfma_f32_16x16x32_bf16(
            af, wp2[(16 + kk) * 256 + tid], acc[1], 0, 0, 0);
    }
}

// Same, both operand sets resident (tree32: no register pressure).
template <int NOUT>
__device__ __forceinline__ void quad_acc_res(
    const __bf16* src, const bf16x8* w2r,
    const float* b2v, int q, int lm, f32x4 (&acc)[2])
{
    const int me = (NOUT >= 16) ? lm : (lm < NOUT ? lm : 0);
    acc[0] = f32x4{ b2v[0], b2v[0], b2v[0], b2v[0] };
    acc[1] = f32x4{ b2v[1], b2v[1], b2v[1], b2v[1] };
#pragma unroll
    for (int kk = 0; kk < 16; ++kk) {
        const bf16x8 af = *(const bf16x8*)
            &src[((kk >> 2) * NOUT + me) * STRIDE + (kk & 3) * 32 + q * 8];
        acc[0] = __builtin_amdgcn_mfma_f32_16x16x32_bf16(
            af, w2r[kk], acc[0], 0, 0, 0);
        acc[1] = __builtin_amdgcn_mfma_f32_16x16x32_bf16(
            af, w2r[16 + kk], acc[1], 0, 0, 0);
    }
}

// bf16 gather of one 64-leaf chunk into PERM rows: leaf 4m+s -> row s*16+m.
// Thread: rows 16i+(tid>>4), leaf id = 4*(tid>>4)+i; 16 lanes x 16B per row.
__device__ __forceinline__ void gissue_bf(
    const int (&ids)[4], const __bf16* etab, int tid, bf16x8 (&st)[4])
{
#pragma unroll
    for (int i = 0; i < 4; ++i)
        st[i] = *(const bf16x8*)(etab + (size_t)ids[i] * 128 + (tid & 15) * 8);
}
__device__ __forceinline__ void gwrite_bf(
    __bf16* dst, int tid, const bf16x8 (&st)[4])
{
#pragma unroll
    for (int i = 0; i < 4; ++i) {
        const int row = 16 * i + (tid >> 4);
        *(bf16x8*)&dst[row * STRIDE + (tid & 15) * 8] = st[i];
    }
}

// fp32 fallback gather of one 64-leaf chunk into the same PERM layout:
// LDS row rt holds leaf 4*(rt&15)+(rt>>4); 32 lanes x 16B per row.
__device__ __forceinline__ void gissue_f32(
    const int* wb64, const float* emb, int tid, f32x4 (&st)[8])
{
#pragma unroll
    for (int i = 0; i < 8; ++i) {
        const int rt = (tid >> 5) + 8 * i;
        const int id = wb64[4 * (rt & 15) + (rt >> 4)];
        st[i] = *(const f32x4*)(emb + (size_t)id * 128 + (tid & 31) * 4);
    }
}
__device__ __forceinline__ void gwrite_f32(
    __bf16* dst, int tid, const f32x4 (&st)[8])
{
#pragma unroll
    for (int i = 0; i < 8; ++i) {
        const int rt = (tid >> 5) + 8 * i;
        *(bf16x4*)&dst[rt * STRIDE + (tid & 31) * 4] =
            __builtin_convertvector(st[i], bf16x4);
    }
}

// Kernel 1: one block = 256 leaves (2048 blocks), quad ladder:
//   4x L12 (64 leaves -> 16 nodes each, into D perm rows r*16+4c+q)
//   L34 (D 64 -> E 16, E overlays bufA rows 0..15, perm rows r*4+q)
//   L56 (E 16 -> 4 roots, straight to y)
// Gather 2-deep rolling (r8), raw barriers. 6 compute phases (was 13).
template <bool BF>
__global__ __launch_bounds__(256, 3) void tree128_kernel(
    const int* __restrict__ wid, const float* __restrict__ emb,
    const __bf16* __restrict__ etab, const __bf16* __restrict__ wpack2,
    const float* __restrict__ b2, __bf16* __restrict__ yout)
{
    __shared__ __align__(16) __bf16 bufA[64 * STRIDE];  // 17408 B (E = rows 0..15)
    __shared__ __align__(16) __bf16 bufB[64 * STRIDE];  // 17408 B
    __shared__ __align__(16) __bf16 bufD[64 * STRIDE];  // 17408 B -> 52224 total
    const int tid = threadIdx.x;
    const int batch = blockIdx.x >> 3;   // 8 blocks (256 leaves) per batch
    const int pair = blockIdx.x & 7;
    const int wv = tid >> 6, ln = tid & 63, q = ln >> 4, lm = ln & 15;

    // Resident W2 frags, nl=0 half: 16 x 16B = 64 regs.
    const bf16x8* wp2 = (const bf16x8*)wpack2;
    bf16x8 wres[16];
#pragma unroll
    for (int f = 0; f < 16; ++f) wres[f] = wp2[f * 256 + tid];
    float b2v[2];
    b2v[0] = b2[(2 * wv + 0) * 16 + lm];
    b2v[1] = b2[(2 * wv + 1) * 16 + lm];

    const int* wb = wid + batch * 2048 + pair * 256;

    // L12 phase: chunk c from src buf -> D rows r*16 + 4c + q.
    auto L12 = [&](const __bf16* src, int c) {
        f32x4 a2[2];
        quad_acc_stream<16>(src, wres, wp2, b2v, tid, q, lm, a2);
#pragma unroll
        for (int nl = 0; nl < 2; ++nl) {
            const int col = (2 * wv + nl) * 16 + lm;
            const bf16x4 hv = __builtin_convertvector(a2[nl], bf16x4);
#pragma unroll
            for (int r = 0; r < 4; ++r)
                bufD[(r * 16 + 4 * c + q) * STRIDE + col] = hv[r];
        }
    };

    if constexpr (BF) {
        int ids[4][4];
#pragma unroll
        for (int c = 0; c < 4; ++c)
#pragma unroll
            for (int i = 0; i < 4; ++i)
                ids[c][i] = wb[64 * c + 4 * (tid >> 4) + i];
        bf16x8 s1[4], s2[4];
        gissue_bf(ids[0], etab, tid, s1);
        gissue_bf(ids[1], etab, tid, s2);
        gwrite_bf(bufA, tid, s1);
        BARRIER();
        gissue_bf(ids[2], etab, tid, s1);
        L12(bufA, 0);
        gwrite_bf(bufB, tid, s2);          // B untouched: safe this phase
        BARRIER();
        gissue_bf(ids[3], etab, tid, s2);
        L12(bufB, 1);
        gwrite_bf(bufA, tid, s1);          // A dead (L12(0) done at prev BAR)
        BARRIER();
        L12(bufA, 2);
        gwrite_bf(bufB, tid, s2);
        BARRIER();
        L12(bufB, 3);
        BARRIER();
    } else {
        f32x4 st[8];
        gissue_f32(wb, emb, tid, st);
        gwrite_f32(bufA, tid, st);
        BARRIER();
        gissue_f32(wb + 64, emb, tid, st);
        L12(bufA, 0);
        gwrite_f32(bufB, tid, st);
        BARRIER();
        gissue_f32(wb + 128, emb, tid, st);
        L12(bufB, 1);
        gwrite_f32(bufA, tid, st);
        BARRIER();
        gissue_f32(wb + 192, emb, tid, st);
        L12(bufA, 2);
        gwrite_f32(bufB, tid, st);
        BARRIER();
        L12(bufB, 3);
        BARRIER();
    }

    // L34: D (64 perm rows) -> E (16 perm rows r*4+q, overlaying bufA).
    {
        f32x4 a2[2];
        quad_acc_stream<16>(bufD, wres, wp2, b2v, tid, q, lm, a2);
#pragma unroll
        for (int nl = 0; nl < 2; ++nl) {
            const int col = (2 * wv + nl) * 16 + lm;
            const bf16x4 hv = __builtin_convertvector(a2[nl], bf16x4);
#pragma unroll
            for (int r = 0; r < 4; ++r)
                bufA[(r * 4 + q) * STRIDE + col] = hv[r];
        }
    }
    BARRIER();
    // L56: E (16) -> 4 roots straight to y (bf16).
    {
        f32x4 a2[2];
        quad_acc_stream<4>(bufA, wres, wp2, b2v, tid, q, lm, a2);
        __bf16* yrow = yout + (size_t)(batch * 32 + pair * 4) * 128;
#pragma unroll
        for (int nl = 0; nl < 2; ++nl) {
            const int col = (2 * wv + nl) * 16 + lm;
            if (q == 0) {
#pragma unroll
                for (int r = 0; r < 4; ++r)
                    yrow[r * 128 + col] = (__bf16)a2[nl][r];
            }
        }
    }
}

// Kernel 2: one block = one batch; 32 roots ->(quad) 8 ->(quad) 2 ->(W1) 1.
__global__ __launch_bounds__(256) void tree32_kernel(
    const __bf16* __restrict__ yin, const __bf16* __restrict__ wpack1,
    const __bf16* __restrict__ wpack2, const float* __restrict__ b2,
    const float* __restrict__ bias, float* __restrict__ out)
{
    __shared__ __align__(16) __bf16 buf0[32 * STRIDE];  // 8704 B
    __shared__ __align__(16) __bf16 buf1[8 * STRIDE];   // 2176 B
    const int tid = threadIdx.x;
    const int batch = blockIdx.x;
    const int wv = tid >> 6, ln = tid & 63, q = ln >> 4, lm = ln & 15;

    bf16x8 w2r[32];
    const bf16x8* wp2 = (const bf16x8*)wpack2;
#pragma unroll
    for (int f = 0; f < 32; ++f) w2r[f] = wp2[f * 256 + tid];
    bf16x8 w1r[16];
    const bf16x8* wp1 = (const bf16x8*)wpack1;
#pragma unroll
    for (int f = 0; f < 16; ++f) w1r[f] = wp1[f * 256 + tid];
    float b2v[2], b1v[2];
    b2v[0] = b2[(2 * wv + 0) * 16 + lm];
    b2v[1] = b2[(2 * wv + 1) * 16 + lm];
    b1v[0] = bias[(2 * wv + 0) * 16 + lm];
    b1v[1] = bias[(2 * wv + 1) * 16 + lm];

    // Load 32 roots at PERM rows (o&3)*8 + (o>>2) for the NOUT=8 quad read.
#pragma unroll
    for (int i = 0; i < 2; ++i) {
        const int flat = tid + 256 * i;
        const int o = flat >> 4;
        const int c8 = flat & 15;
        const bf16x8 v =
            *(const bf16x8*)(yin + (size_t)(batch * 32 + o) * 128 + c8 * 8);
        *(bf16x8*)&buf0[((o & 3) * 8 + (o >> 2)) * STRIDE + c8 * 8] = v;
    }
    __syncthreads();

    // Q1: 32 -> 8 (perm rows r*2+q for the NOUT=2 read).
    {
        f32x4 a2[2];
        quad_acc_res<8>(buf0, w2r, b2v, q, lm, a2);
#pragma unroll
        for (int nl = 0; nl < 2; ++nl) {
            const int col = (2 * wv + nl) * 16 + lm;
            const bf16x4 hv = __builtin_convertvector(a2[nl], bf16x4);
            if (q < 2) {
#pragma unroll
                for (int r = 0; r < 4; ++r)
                    buf1[(r * 2 + q) * STRIDE + col] = hv[r];
            }
        }
    }
    __syncthreads();
    // Q2: 8 -> 2 (plain rows 0,1 for the W1 final).
    {
        f32x4 a2[2];
        quad_acc_res<2>(buf1, w2r, b2v, q, lm, a2);
#pragma unroll
        for (int nl = 0; nl < 2; ++nl) {
            const int col = (2 * wv + nl) * 16 + lm;
            const bf16x4 hv = __builtin_convertvector(a2[nl], bf16x4);
            if (q == 0) {
#pragma unroll
                for (int r = 0; r < 2; ++r)
                    buf0[r * STRIDE + col] = hv[r];
            }
        }
    }
    __syncthreads();
    // Final: rows 0,1 (K=256, W1, bias b) -> fp32 root row.
    {
        f32x4 acc[2];
        acc[0] = f32x4{ b1v[0], b1v[0], b1v[0], b1v[0] };
        acc[1] = f32x4{ b1v[1], b1v[1], b1v[1], b1v[1] };
#pragma unroll
        for (int kh = 0; kh < 2; ++kh) {
            bf16x8 af[4];
#pragma unroll
            for (int j = 0; j < 4; ++j)
                af[j] = *(const bf16x8*)&buf0[kh * STRIDE + j * 32 + q * 8];
#pragma unroll
            for (int nl = 0; nl < 2; ++nl)
#pragma unroll
                for (int j = 0; j < 4; ++j)
                    acc[nl] = __builtin_amdgcn_mfma_f32_16x16x32_bf16(
                        af[j], w1r[nl * 8 + kh * 4 + j], acc[nl], 0, 0, 0);
        }
#pragma unroll
        for (int nl = 0; nl < 2; ++nl) {
            const int col = (2 * wv + nl) * 16 + lm;
            if (q == 0) out[(size_t)batch * 128 + col] = acc[nl][0];
        }
    }
}

extern "C" void kernel_launch(void* const* d_in, const int* in_sizes, int n_in,
                              void* d_out, int out_size, void* d_ws, size_t ws_size,
                              hipStream_t stream) {
    const int*   wid = (const int*)d_in[0];      // (256, 2048) int32
    const float* emb = (const float*)d_in[1];    // (100000, 128) fp32
    const float* W   = (const float*)d_in[2];    // (128, 256) fp32
    const float* b   = (const float*)d_in[3];    // (128,) fp32
    float* out = (float*)d_out;                  // (256, 128) fp32

    __bf16* wpack1 = (__bf16*)d_ws;              // 32768 bf16 = 64 KB
    __bf16* wpack2 = wpack1 + 32768;             // 65536 bf16 = 128 KB
    float*  b2     = (float*)(wpack2 + 65536);   // 128 f32 = 512 B
    __bf16* y      = (__bf16*)(b2 + 128);        // (256,32,128) bf16 = 2 MB
    __bf16* etab   = y + 256 * 32 * 128;         // (100000,128) bf16 = 25.6 MB

    const size_t need_full = (size_t)(32768 + 65536) * 2 + 512
                           + (size_t)256 * 32 * 128 * 2
                           + (size_t)100000 * 128 * 2;   // ~27.9 MB
    const bool bf = (ws_size >= need_full);
    const int n8 = bf ? (100000 * 128 / 8) : 0;

    prep_kernel<<<2048, 256, 0, stream>>>(W, b, emb, wpack1, wpack2, b2,
                                          etab, n8);
    if (bf)
        tree128_kernel<true><<<2048, 256, 0, stream>>>(
            wid, emb, etab, wpack2, b2, y);
    else
        tree128_kernel<false><<<2048, 256, 0, stream>>>(
            wid, emb, etab, wpack2, b2, y);
    tree32_kernel<<<256, 256, 0, stream>>>(y, wpack1, wpack2, b2, b, out);
}